// Round 8
// baseline (220.396 us; speedup 1.0000x reference)
//
#include <hip/hip_runtime.h>

// Problem constants
#define B_   8
#define TE_  256
#define TD_  256
#define D_   256
#define U_   256

// Workspace layout (float offsets). ~6 MB.
#define EET_OFF   0        // (B, U, TE)  Ee^T = exp2(2log2e * en@w_en), TRANSPOSED
#define ED_OFF    524288   // (B, TD, U)  Ed = exp2(2log2e * de@w_de)
#define ALPHA_OFF 1048576  // (B, TD, TE) alphas
#define MAXMU_OFF 1572864  // (B, TD)     row max of mu'

__device__ __forceinline__ float fexp2(float x) {
#if __has_builtin(__builtin_amdgcn_exp2f)
  return __builtin_amdgcn_exp2f(x);
#else
  return exp2f(x);
#endif
}
__device__ __forceinline__ float frcp(float x) {
#if __has_builtin(__builtin_amdgcn_rcpf)
  return __builtin_amdgcn_rcpf(x);
#else
  return 1.0f / x;
#endif
}
__device__ __forceinline__ float rdlane(float v, int l) {
  return __int_as_float(__builtin_amdgcn_readlane(__float_as_int(v), l));
}

#define LOG2E_F 1.4426950408889634f
#define TWO_LOG2E_F 2.8853900817779268f

// ---------------------------------------------------------------------------
// K1: block = 16 rows x 256 u (u = tid: NO W duplication across waves --
// R6/R7's fatal flaw was 512 MB of duplicated W reads at the L2 ceiling).
// W reuse (64x/block) staged in LDS in 32-k chunks, register-double-buffered:
// next chunk's global loads are issued before compute so latency overlaps.
// Compute: ONE ds_read_b32 per k (5.8 cyc; 4 waves = 23 cyc/CU < 32 VALU
// cyc -> VALU-bound). A rows: block-uniform float4 -> s_load (1:8 ratio,
// batched by compiler; SGPR operand free in v_fma). grid 256 (1 blk/CU):
// bi<128: en -> EeT[b][u][t] (per-thread contiguous stores), else de -> Ed.
// ---------------------------------------------------------------------------
__global__ __launch_bounds__(256) void coatt_k1_proj(
    const float* __restrict__ en, const float* __restrict__ de,
    const float* __restrict__ w_en, const float* __restrict__ w_de,
    float* __restrict__ ws) {
  const int bi = blockIdx.x;
  const int which = bi >> 7;                 // 0: en, 1: de
  const float* __restrict__ A = which ? de : en;      // (2048, 256)
  const float* __restrict__ W = which ? w_de : w_en;  // (256, 256) k-major
  const int rowBase = (bi & 127) * 16;
  const int tid = threadIdx.x;
  const int w = tid >> 6, lane = tid & 63;

  __shared__ float Wlds[2][32 * 256];  // 64 KB: two 32-k x 256-u chunks

  // staging: wave w copies 8 KB of the 32 KB chunk; f in [0,32) instrs of 1 KB
  const int stOff = (w * 8) * 256 + lane * 4;  // float offset of this wave's first float4

  float4 stg[8];
  // prologue: load chunk 0 into regs, write buf 0
#pragma unroll
  for (int i = 0; i < 8; ++i) stg[i] = *(const float4*)&W[stOff + i * 256];
#pragma unroll
  for (int i = 0; i < 8; ++i) *(float4*)&Wlds[0][stOff + i * 256] = stg[i];

  float acc[16] = {};
  for (int c = 0; c < 8; ++c) {
    __syncthreads();  // buf[c&1] ready
    if (c < 7) {      // issue next chunk's loads; in flight during compute
#pragma unroll
      for (int i = 0; i < 8; ++i)
        stg[i] = *(const float4*)&W[(c + 1) * 8192 + stOff + i * 256];
    }
    const float* __restrict__ wb = &Wlds[c & 1][0];
#pragma unroll
    for (int q = 0; q < 8; ++q) {
      const float w0 = wb[(q * 4 + 0) * 256 + tid];
      const float w1 = wb[(q * 4 + 1) * 256 + tid];
      const float w2 = wb[(q * 4 + 2) * 256 + tid];
      const float w3 = wb[(q * 4 + 3) * 256 + tid];
#pragma unroll
      for (int r = 0; r < 16; ++r) {
        const float4 a4 = *(const float4*)&A[(rowBase + r) * D_ + c * 32 + q * 4];  // uniform
        acc[r] = fmaf(a4.x, w0, acc[r]);
        acc[r] = fmaf(a4.y, w1, acc[r]);
        acc[r] = fmaf(a4.z, w2, acc[r]);
        acc[r] = fmaf(a4.w, w3, acc[r]);
      }
    }
    if (c < 7) {
      __syncthreads();  // all reads of buf[(c+1)&1] from iter c-1 done
#pragma unroll
      for (int i = 0; i < 8; ++i) *(float4*)&Wlds[(c + 1) & 1][stOff + i * 256] = stg[i];
    }
  }

  if (which) {
    float* __restrict__ out = ws + ED_OFF;
#pragma unroll
    for (int r = 0; r < 16; ++r)
      out[(rowBase + r) * U_ + tid] = fexp2(acc[r] * TWO_LOG2E_F);  // coalesced
  } else {
    const int b = rowBase >> 8, t0 = rowBase & 255;
    float* __restrict__ p = ws + EET_OFF + (size_t)(b * U_ + tid) * TE_ + t0;
#pragma unroll
    for (int q = 0; q < 4; ++q) {
      float4 o;
      o.x = fexp2(acc[q * 4 + 0] * TWO_LOG2E_F);
      o.y = fexp2(acc[q * 4 + 1] * TWO_LOG2E_F);
      o.z = fexp2(acc[q * 4 + 2] * TWO_LOG2E_F);
      o.w = fexp2(acc[q * 4 + 3] * TWO_LOG2E_F);
      *(float4*)&p[q * 4] = o;  // per-thread contiguous
    }
  }
}

// ---------------------------------------------------------------------------
// K2 (trans-pipe-bound, R4-proven form): block (b, 4 s-rows), thread t = tid.
//   mu'[s][t] = -2 * sum_u nu_u * rcp(fma(Ed[s,u], EeT[u,t], 1))
// EeT: coalesced dword (lane=t). Ed/nu: uniform -> s_load (1:19 ratio, benign).
// Fused row-softmax over t. grid (64, 8) = 512 blocks.
// ---------------------------------------------------------------------------
__global__ __launch_bounds__(256) void coatt_k2_mu(
    const float* __restrict__ nu, float* __restrict__ ws) {
  float* __restrict__ alphas = ws + ALPHA_OFF;
  float* __restrict__ maxmu = ws + MAXMU_OFF;
  const int b = blockIdx.y;
  const int sBase = blockIdx.x * 4;
  const int tid = threadIdx.x;
  const int w = tid >> 6, lane = tid & 63;
  const float* __restrict__ Ee_b = ws + EET_OFF + (size_t)b * U_ * TE_ + tid;
  const float* __restrict__ Ed_b = ws + ED_OFF + (size_t)(b * TD_ + sBase) * U_;

  float acc0 = 0.f, acc1 = 0.f, acc2 = 0.f, acc3 = 0.f;
#pragma unroll 4
  for (int u4 = 0; u4 < 64; ++u4) {
    const float4 nv = *(const float4*)&nu[u4 * 4];            // s_load
    const float4 e0 = *(const float4*)&Ed_b[0 * U_ + u4 * 4]; // s_load
    const float4 e1 = *(const float4*)&Ed_b[1 * U_ + u4 * 4];
    const float4 e2 = *(const float4*)&Ed_b[2 * U_ + u4 * 4];
    const float4 e3 = *(const float4*)&Ed_b[3 * U_ + u4 * 4];
    float ee[4];
#pragma unroll
    for (int j = 0; j < 4; ++j) ee[j] = Ee_b[(u4 * 4 + j) * TE_];  // coalesced
    const float* nvp = (const float*)&nv;
    const float* p0 = (const float*)&e0;
    const float* p1 = (const float*)&e1;
    const float* p2 = (const float*)&e2;
    const float* p3 = (const float*)&e3;
#pragma unroll
    for (int j = 0; j < 4; ++j) {
      acc0 = fmaf(nvp[j], frcp(fmaf(p0[j], ee[j], 1.0f)), acc0);
      acc1 = fmaf(nvp[j], frcp(fmaf(p1[j], ee[j], 1.0f)), acc1);
      acc2 = fmaf(nvp[j], frcp(fmaf(p2[j], ee[j], 1.0f)), acc2);
      acc3 = fmaf(nvp[j], frcp(fmaf(p3[j], ee[j], 1.0f)), acc3);
    }
  }
  // mu' = -2*acc. Fused softmax over t (256 threads = 4 waves).
  float v[4] = {-2.f * acc0, -2.f * acc1, -2.f * acc2, -2.f * acc3};
  __shared__ float part[4][4];  // [s][wave]
  float m[4];
#pragma unroll
  for (int s = 0; s < 4; ++s) {
    m[s] = v[s];
#pragma unroll
    for (int off = 32; off > 0; off >>= 1) m[s] = fmaxf(m[s], __shfl_xor(m[s], off));
    if (lane == 0) part[s][w] = m[s];
  }
  __syncthreads();
#pragma unroll
  for (int s = 0; s < 4; ++s)
    m[s] = fmaxf(fmaxf(part[s][0], part[s][1]), fmaxf(part[s][2], part[s][3]));
  __syncthreads();
  float e[4], sm[4];
#pragma unroll
  for (int s = 0; s < 4; ++s) {
    e[s] = fexp2((v[s] - m[s]) * LOG2E_F);
    sm[s] = e[s];
#pragma unroll
    for (int off = 32; off > 0; off >>= 1) sm[s] += __shfl_xor(sm[s], off);
    if (lane == 0) part[s][w] = sm[s];
  }
  __syncthreads();
  float* __restrict__ al = alphas + (size_t)(b * TD_ + sBase) * TE_;
#pragma unroll
  for (int s = 0; s < 4; ++s) {
    const float tot = (part[s][0] + part[s][1]) + (part[s][2] + part[s][3]);
    al[s * TE_ + tid] = e[s] * frcp(tot);
  }
  if (tid == 0) {
#pragma unroll
    for (int s = 0; s < 4; ++s) maxmu[b * TD_ + sBase + s] = m[s];
  }
}

// ---------------------------------------------------------------------------
// K4 (fused K3+K4, R4-proven operand routing): per block (b, 4 s-rows),
// thread d = tid.
//  a) max_alphas = softmax_s(maxmu[b,:]) per-wave in registers (no barrier)
//  b) hh[d] = sum_s de[b,s,d]*malpha[s] (coalesced de, rdlane broadcast)
//  c) sum_en[s,d] = sum_t alphas[s,t]*en[t,d]: alphas s_load, en coalesced
//  d) concat: out = [de | sum_en | de*sum_en | de*hh]
// grid (64, 8) = 512 blocks.
// ---------------------------------------------------------------------------
__global__ __launch_bounds__(256) void coatt_k4_out(
    const float* __restrict__ en, const float* __restrict__ de,
    const float* __restrict__ ws, float* __restrict__ out) {
  const float* __restrict__ maxmu = ws + MAXMU_OFF;
  const int b = blockIdx.y;
  const int sBase = blockIdx.x * 4;
  const int tid = threadIdx.x;
  const int lane = tid & 63;
  const int d = tid;

  // (a) malpha in registers, redundant per wave
  float4 mv = *(const float4*)&maxmu[b * TD_ + lane * 4];
  float mx = fmaxf(fmaxf(mv.x, mv.y), fmaxf(mv.z, mv.w));
#pragma unroll
  for (int off = 32; off > 0; off >>= 1) mx = fmaxf(mx, __shfl_xor(mx, off));
  float4 ex;
  ex.x = fexp2((mv.x - mx) * LOG2E_F);
  ex.y = fexp2((mv.y - mx) * LOG2E_F);
  ex.z = fexp2((mv.z - mx) * LOG2E_F);
  ex.w = fexp2((mv.w - mx) * LOG2E_F);
  float ss = (ex.x + ex.y) + (ex.z + ex.w);
#pragma unroll
  for (int off = 32; off > 0; off >>= 1) ss += __shfl_xor(ss, off);
  const float inv = frcp(ss);
  float mal[4] = {ex.x * inv, ex.y * inv, ex.z * inv, ex.w * inv};

  // (b) hh for this thread's d
  const float* __restrict__ de_b = de + (size_t)b * TD_ * D_ + d;
  float hh = 0.f;
#pragma unroll 8
  for (int s4 = 0; s4 < 64; ++s4) {
#pragma unroll
    for (int c = 0; c < 4; ++c)
      hh = fmaf(de_b[(s4 * 4 + c) * D_], rdlane(mal[c], s4), hh);
  }

  // (c) sum_en: alphas s_load (uniform), en coalesced
  const float* __restrict__ al = ws + ALPHA_OFF + (size_t)(b * TD_ + sBase) * TE_;
  const float* __restrict__ en_b = en + (size_t)b * TE_ * D_ + d;
  float acc0 = 0.f, acc1 = 0.f, acc2 = 0.f, acc3 = 0.f;
#pragma unroll 4
  for (int t4 = 0; t4 < 64; ++t4) {
    const float4 a0 = *(const float4*)&al[0 * TE_ + t4 * 4];  // s_load
    const float4 a1 = *(const float4*)&al[1 * TE_ + t4 * 4];
    const float4 a2 = *(const float4*)&al[2 * TE_ + t4 * 4];
    const float4 a3 = *(const float4*)&al[3 * TE_ + t4 * 4];
    float env[4];
#pragma unroll
    for (int j = 0; j < 4; ++j) env[j] = en_b[(t4 * 4 + j) * D_];  // coalesced
    const float* q0 = (const float*)&a0;
    const float* q1 = (const float*)&a1;
    const float* q2 = (const float*)&a2;
    const float* q3 = (const float*)&a3;
#pragma unroll
    for (int j = 0; j < 4; ++j) {
      acc0 = fmaf(q0[j], env[j], acc0);
      acc1 = fmaf(q1[j], env[j], acc1);
      acc2 = fmaf(q2[j], env[j], acc2);
      acc3 = fmaf(q3[j], env[j], acc3);
    }
  }

  // (d) concat epilogue
  const float se[4] = {acc0, acc1, acc2, acc3};
#pragma unroll
  for (int s = 0; s < 4; ++s) {
    const float dd = de[(size_t)(b * TD_ + sBase + s) * D_ + d];
    float* o = out + (size_t)(b * TD_ + sBase + s) * (4 * D_);
    o[d] = dd;
    o[D_ + d] = se[s];
    o[2 * D_ + d] = dd * se[s];
    o[3 * D_ + d] = dd * hh;
  }
}

extern "C" void kernel_launch(void* const* d_in, const int* in_sizes, int n_in,
                              void* d_out, int out_size, void* d_ws, size_t ws_size,
                              hipStream_t stream) {
  (void)in_sizes; (void)n_in; (void)out_size; (void)ws_size;
  const float* en   = (const float*)d_in[0];
  const float* de   = (const float*)d_in[1];
  const float* w_en = (const float*)d_in[2];
  const float* w_de = (const float*)d_in[3];
  const float* nu   = (const float*)d_in[4];
  float* out = (float*)d_out;
  float* ws  = (float*)d_ws;

  coatt_k1_proj<<<dim3(256), 256, 0, stream>>>(en, de, w_en, w_de, ws);
  coatt_k2_mu<<<dim3(64, 8), 256, 0, stream>>>(nu, ws);
  coatt_k4_out<<<dim3(64, 8), 256, 0, stream>>>(en, de, ws, out);
}

// Round 9
// 136.414 us; speedup vs baseline: 1.6156x; 1.6156x over previous
//
#include <hip/hip_runtime.h>

// Problem constants
#define B_   8
#define TE_  256
#define TD_  256
#define D_   256
#define U_   256

// Workspace layout (float offsets). ~6 MB.
#define EET_OFF   0        // (B, U, TE)  Ee^T = exp2(2log2e * en@w_en), TRANSPOSED
#define ED_OFF    524288   // (B, TD, U)  Ed = exp2(2log2e * de@w_de)
#define ALPHA_OFF 1048576  // (B, TD, TE) alphas
#define MAXMU_OFF 1572864  // (B, TD)     row max of mu'

__device__ __forceinline__ float fexp2(float x) {
#if __has_builtin(__builtin_amdgcn_exp2f)
  return __builtin_amdgcn_exp2f(x);
#else
  return exp2f(x);
#endif
}
__device__ __forceinline__ float frcp(float x) {
#if __has_builtin(__builtin_amdgcn_rcpf)
  return __builtin_amdgcn_rcpf(x);
#else
  return 1.0f / x;
#endif
}
__device__ __forceinline__ float rdlane(float v, int l) {
  return __int_as_float(__builtin_amdgcn_readlane(__float_as_int(v), l));
}

#define LOG2E_F 1.4426950408889634f
#define TWO_LOG2E_F 2.8853900817779268f

// ---------------------------------------------------------------------------
// K1 (W-in-LDS + A-via-readlane, k-split waves): block = 16 rows x 256 u.
// Thread owns 4 u (lane*4) x all 16 rows (acc[16] float4). Wave w covers
// k = c*32 + w*8 .. +7 of each 32-k chunk (so the W chunk is read from LDS
// exactly once per block: 8 ds_read_b128/wave/chunk, preloaded into wv[8]).
// A: 2 cooperative VECTOR loads per chunk per wave (lane -> (row, k)),
// broadcast at use via v_readlane — no s_load latency (R8's 122 us failure),
// no W duplication (R6/R7's 512 MB L2 failure). rdl:fma = 1:4, VALU-bound:
// ~1280 cyc/chunk/wave, ~12K cyc/block ≈ 6 us. Epilogue: cross-wave
// k-reduction through the dead Wlds buffer (64 KB exact overlay).
// grid 256 (1 blk/CU): bi<128 en -> EeT[b][u][t], else de -> Ed[s][u].
// ---------------------------------------------------------------------------
__global__ __launch_bounds__(256, 1) void coatt_k1_proj(
    const float* __restrict__ en, const float* __restrict__ de,
    const float* __restrict__ w_en, const float* __restrict__ w_de,
    float* __restrict__ ws) {
  const int bi = blockIdx.x;
  const int which = bi >> 7;                 // 0: en, 1: de
  const float* __restrict__ A = which ? de : en;      // (2048, 256)
  const float* __restrict__ W = which ? w_de : w_en;  // (256, 256) k-major
  const int rowBase = (bi & 127) * 16;
  const int tid = threadIdx.x;
  const int w = tid >> 6, lane = tid & 63;
  const int u4 = lane * 4;

  __shared__ float Wlds[2][32 * 256];  // 64 KB; reused as reduce buffer

  // W staging: flat float4 f = tid + 256*i (i<8); coalesced b128 both sides.
  float4 stg[8];
#pragma unroll
  for (int i = 0; i < 8; ++i) {
    const int f = tid + 256 * i;
    stg[i] = *(const float4*)&W[(f >> 6) * 256 + (f & 63) * 4];
  }
#pragma unroll
  for (int i = 0; i < 8; ++i) *(float4*)&Wlds[0][(tid + 256 * i) * 4] = stg[i];

  // A coop pointers: lane -> (row = lane>>3, k = w*8 + (lane&7))
  const float* __restrict__ Arow0 =
      A + (size_t)(rowBase + (lane >> 3)) * D_ + w * 8 + (lane & 7);
  const float* __restrict__ Arow1 = Arow0 + 8 * D_;
  float a0c = Arow0[0], a1c = Arow1[0];

  float4 acc[16];
#pragma unroll
  for (int r = 0; r < 16; ++r) acc[r] = {0.f, 0.f, 0.f, 0.f};

  for (int c = 0; c < 8; ++c) {
    __syncthreads();  // Wlds[c&1] fully written; prior-iter reads done
    float a0n = 0.f, a1n = 0.f;
    if (c < 7) {  // next chunk's loads in flight during compute
#pragma unroll
      for (int i = 0; i < 8; ++i) {
        const int f = tid + 256 * i;
        stg[i] = *(const float4*)&W[((c + 1) * 32 + (f >> 6)) * 256 + (f & 63) * 4];
      }
      a0n = Arow0[(c + 1) * 32];
      a1n = Arow1[(c + 1) * 32];
    }
    const float* __restrict__ wb = &Wlds[c & 1][(w * 8) * 256 + u4];
    float4 wv[8];
#pragma unroll
    for (int kk = 0; kk < 8; ++kk) wv[kk] = *(const float4*)&wb[kk * 256];
#pragma unroll
    for (int kk = 0; kk < 8; ++kk) {
#pragma unroll
      for (int r = 0; r < 16; ++r) {
        const float a = rdlane(r < 8 ? a0c : a1c, (r & 7) * 8 + kk);  // static reg+lane
        acc[r].x = fmaf(a, wv[kk].x, acc[r].x);
        acc[r].y = fmaf(a, wv[kk].y, acc[r].y);
        acc[r].z = fmaf(a, wv[kk].z, acc[r].z);
        acc[r].w = fmaf(a, wv[kk].w, acc[r].w);
      }
    }
    if (c < 7) {  // write next buf (safe: others read buf c&1 only)
#pragma unroll
      for (int i = 0; i < 8; ++i)
        *(float4*)&Wlds[(c + 1) & 1][(tid + 256 * i) * 4] = stg[i];
      a0c = a0n;
      a1c = a1n;
    }
  }

  // cross-wave k-reduction: red[ww][16][256] overlays Wlds (64 KB exact)
  __syncthreads();
  float* red = &Wlds[0][0];
#pragma unroll
  for (int r = 0; r < 16; ++r)
    *(float4*)&red[(w * 16 + r) * 256 + u4] = acc[r];
  __syncthreads();
  // wave w owns rows w*4..w*4+3; thread covers u = lane*4..+3
  float4 val[4];
#pragma unroll
  for (int i = 0; i < 4; ++i) {
    float4 s = {0.f, 0.f, 0.f, 0.f};
#pragma unroll
    for (int ww = 0; ww < 4; ++ww) {
      const float4 q = *(const float4*)&red[(ww * 16 + w * 4 + i) * 256 + u4];
      s.x += q.x; s.y += q.y; s.z += q.z; s.w += q.w;
    }
    val[i].x = fexp2(s.x * TWO_LOG2E_F);
    val[i].y = fexp2(s.y * TWO_LOG2E_F);
    val[i].z = fexp2(s.z * TWO_LOG2E_F);
    val[i].w = fexp2(s.w * TWO_LOG2E_F);
  }
  if (which) {
    // Ed[row][u]: coalesced b128, rows rowBase + w*4 + i
    float* __restrict__ out = ws + ED_OFF;
#pragma unroll
    for (int i = 0; i < 4; ++i)
      *(float4*)&out[(rowBase + w * 4 + i) * U_ + u4] = val[i];
  } else {
    // EeT[b][u][t]: for each of the 4 u's, store rows w*4..w*4+3 as one f4
    const int b = rowBase >> 8, t0 = rowBase & 255;
    float* __restrict__ outb = ws + EET_OFF + (size_t)b * U_ * TE_ + t0 + w * 4;
#pragma unroll
    for (int j = 0; j < 4; ++j) {
      float4 o;
      o.x = ((const float*)&val[0])[j];
      o.y = ((const float*)&val[1])[j];
      o.z = ((const float*)&val[2])[j];
      o.w = ((const float*)&val[3])[j];
      *(float4*)&outb[(size_t)(u4 + j) * TE_] = o;
    }
  }
}

// ---------------------------------------------------------------------------
// K2 (trans-pipe-bound, R4-proven form): block (b, 4 s-rows), thread t = tid.
//   mu'[s][t] = -2 * sum_u nu_u * rcp(fma(Ed[s,u], EeT[u,t], 1))
// EeT: coalesced dword (lane=t). Ed/nu: uniform -> s_load (benign ratio).
// Fused row-softmax over t. grid (64, 8) = 512 blocks.
// ---------------------------------------------------------------------------
__global__ __launch_bounds__(256) void coatt_k2_mu(
    const float* __restrict__ nu, float* __restrict__ ws) {
  float* __restrict__ alphas = ws + ALPHA_OFF;
  float* __restrict__ maxmu = ws + MAXMU_OFF;
  const int b = blockIdx.y;
  const int sBase = blockIdx.x * 4;
  const int tid = threadIdx.x;
  const int w = tid >> 6, lane = tid & 63;
  const float* __restrict__ Ee_b = ws + EET_OFF + (size_t)b * U_ * TE_ + tid;
  const float* __restrict__ Ed_b = ws + ED_OFF + (size_t)(b * TD_ + sBase) * U_;

  float acc0 = 0.f, acc1 = 0.f, acc2 = 0.f, acc3 = 0.f;
#pragma unroll 4
  for (int u4 = 0; u4 < 64; ++u4) {
    const float4 nv = *(const float4*)&nu[u4 * 4];            // s_load
    const float4 e0 = *(const float4*)&Ed_b[0 * U_ + u4 * 4]; // s_load
    const float4 e1 = *(const float4*)&Ed_b[1 * U_ + u4 * 4];
    const float4 e2 = *(const float4*)&Ed_b[2 * U_ + u4 * 4];
    const float4 e3 = *(const float4*)&Ed_b[3 * U_ + u4 * 4];
    float ee[4];
#pragma unroll
    for (int j = 0; j < 4; ++j) ee[j] = Ee_b[(u4 * 4 + j) * TE_];  // coalesced
    const float* nvp = (const float*)&nv;
    const float* p0 = (const float*)&e0;
    const float* p1 = (const float*)&e1;
    const float* p2 = (const float*)&e2;
    const float* p3 = (const float*)&e3;
#pragma unroll
    for (int j = 0; j < 4; ++j) {
      acc0 = fmaf(nvp[j], frcp(fmaf(p0[j], ee[j], 1.0f)), acc0);
      acc1 = fmaf(nvp[j], frcp(fmaf(p1[j], ee[j], 1.0f)), acc1);
      acc2 = fmaf(nvp[j], frcp(fmaf(p2[j], ee[j], 1.0f)), acc2);
      acc3 = fmaf(nvp[j], frcp(fmaf(p3[j], ee[j], 1.0f)), acc3);
    }
  }
  // mu' = -2*acc. Fused softmax over t (256 threads = 4 waves).
  float v[4] = {-2.f * acc0, -2.f * acc1, -2.f * acc2, -2.f * acc3};
  __shared__ float part[4][4];  // [s][wave]
  float m[4];
#pragma unroll
  for (int s = 0; s < 4; ++s) {
    m[s] = v[s];
#pragma unroll
    for (int off = 32; off > 0; off >>= 1) m[s] = fmaxf(m[s], __shfl_xor(m[s], off));
    if (lane == 0) part[s][w] = m[s];
  }
  __syncthreads();
#pragma unroll
  for (int s = 0; s < 4; ++s)
    m[s] = fmaxf(fmaxf(part[s][0], part[s][1]), fmaxf(part[s][2], part[s][3]));
  __syncthreads();
  float e[4], sm[4];
#pragma unroll
  for (int s = 0; s < 4; ++s) {
    e[s] = fexp2((v[s] - m[s]) * LOG2E_F);
    sm[s] = e[s];
#pragma unroll
    for (int off = 32; off > 0; off >>= 1) sm[s] += __shfl_xor(sm[s], off);
    if (lane == 0) part[s][w] = sm[s];
  }
  __syncthreads();
  float* __restrict__ al = alphas + (size_t)(b * TD_ + sBase) * TE_;
#pragma unroll
  for (int s = 0; s < 4; ++s) {
    const float tot = (part[s][0] + part[s][1]) + (part[s][2] + part[s][3]);
    al[s * TE_ + tid] = e[s] * frcp(tot);
  }
  if (tid == 0) {
#pragma unroll
    for (int s = 0; s < 4; ++s) maxmu[b * TD_ + sBase + s] = m[s];
  }
}

// ---------------------------------------------------------------------------
// K4 (fused K3+K4, R4-proven operand routing): per block (b, 4 s-rows),
// thread d = tid.
//  a) max_alphas = softmax_s(maxmu[b,:]) per-wave in registers (no barrier)
//  b) hh[d] = sum_s de[b,s,d]*malpha[s] (coalesced de, rdlane broadcast)
//  c) sum_en[s,d] = sum_t alphas[s,t]*en[t,d]: alphas s_load, en coalesced
//  d) concat: out = [de | sum_en | de*sum_en | de*hh]
// grid (64, 8) = 512 blocks.
// ---------------------------------------------------------------------------
__global__ __launch_bounds__(256) void coatt_k4_out(
    const float* __restrict__ en, const float* __restrict__ de,
    const float* __restrict__ ws, float* __restrict__ out) {
  const float* __restrict__ maxmu = ws + MAXMU_OFF;
  const int b = blockIdx.y;
  const int sBase = blockIdx.x * 4;
  const int tid = threadIdx.x;
  const int lane = tid & 63;
  const int d = tid;

  // (a) malpha in registers, redundant per wave
  float4 mv = *(const float4*)&maxmu[b * TD_ + lane * 4];
  float mx = fmaxf(fmaxf(mv.x, mv.y), fmaxf(mv.z, mv.w));
#pragma unroll
  for (int off = 32; off > 0; off >>= 1) mx = fmaxf(mx, __shfl_xor(mx, off));
  float4 ex;
  ex.x = fexp2((mv.x - mx) * LOG2E_F);
  ex.y = fexp2((mv.y - mx) * LOG2E_F);
  ex.z = fexp2((mv.z - mx) * LOG2E_F);
  ex.w = fexp2((mv.w - mx) * LOG2E_F);
  float ss = (ex.x + ex.y) + (ex.z + ex.w);
#pragma unroll
  for (int off = 32; off > 0; off >>= 1) ss += __shfl_xor(ss, off);
  const float inv = frcp(ss);
  float mal[4] = {ex.x * inv, ex.y * inv, ex.z * inv, ex.w * inv};

  // (b) hh for this thread's d
  const float* __restrict__ de_b = de + (size_t)b * TD_ * D_ + d;
  float hh = 0.f;
#pragma unroll 8
  for (int s4 = 0; s4 < 64; ++s4) {
#pragma unroll
    for (int c = 0; c < 4; ++c)
      hh = fmaf(de_b[(s4 * 4 + c) * D_], rdlane(mal[c], s4), hh);
  }

  // (c) sum_en: alphas s_load (uniform), en coalesced
  const float* __restrict__ al = ws + ALPHA_OFF + (size_t)(b * TD_ + sBase) * TE_;
  const float* __restrict__ en_b = en + (size_t)b * TE_ * D_ + d;
  float acc0 = 0.f, acc1 = 0.f, acc2 = 0.f, acc3 = 0.f;
#pragma unroll 4
  for (int t4 = 0; t4 < 64; ++t4) {
    const float4 a0 = *(const float4*)&al[0 * TE_ + t4 * 4];  // s_load
    const float4 a1 = *(const float4*)&al[1 * TE_ + t4 * 4];
    const float4 a2 = *(const float4*)&al[2 * TE_ + t4 * 4];
    const float4 a3 = *(const float4*)&al[3 * TE_ + t4 * 4];
    float env[4];
#pragma unroll
    for (int j = 0; j < 4; ++j) env[j] = en_b[(t4 * 4 + j) * D_];  // coalesced
    const float* q0 = (const float*)&a0;
    const float* q1 = (const float*)&a1;
    const float* q2 = (const float*)&a2;
    const float* q3 = (const float*)&a3;
#pragma unroll
    for (int j = 0; j < 4; ++j) {
      acc0 = fmaf(q0[j], env[j], acc0);
      acc1 = fmaf(q1[j], env[j], acc1);
      acc2 = fmaf(q2[j], env[j], acc2);
      acc3 = fmaf(q3[j], env[j], acc3);
    }
  }

  // (d) concat epilogue
  const float se[4] = {acc0, acc1, acc2, acc3};
#pragma unroll
  for (int s = 0; s < 4; ++s) {
    const float dd = de[(size_t)(b * TD_ + sBase + s) * D_ + d];
    float* o = out + (size_t)(b * TD_ + sBase + s) * (4 * D_);
    o[d] = dd;
    o[D_ + d] = se[s];
    o[2 * D_ + d] = dd * se[s];
    o[3 * D_ + d] = dd * hh;
  }
}

extern "C" void kernel_launch(void* const* d_in, const int* in_sizes, int n_in,
                              void* d_out, int out_size, void* d_ws, size_t ws_size,
                              hipStream_t stream) {
  (void)in_sizes; (void)n_in; (void)out_size; (void)ws_size;
  const float* en   = (const float*)d_in[0];
  const float* de   = (const float*)d_in[1];
  const float* w_en = (const float*)d_in[2];
  const float* w_de = (const float*)d_in[3];
  const float* nu   = (const float*)d_in[4];
  float* out = (float*)d_out;
  float* ws  = (float*)d_ws;

  coatt_k1_proj<<<dim3(256), 256, 0, stream>>>(en, de, w_en, w_de, ws);
  coatt_k2_mu<<<dim3(64, 8), 256, 0, stream>>>(nu, ws);
  coatt_k4_out<<<dim3(64, 8), 256, 0, stream>>>(en, de, ws, out);
}